// Round 1
// baseline (1855.633 us; speedup 1.0000x reference)
//
#include <hip/hip_runtime.h>

#define T_ 32
#define B_ 32
#define S_ 64
#define C_ 1024
#define H_ 1024
#define A_ 128

// ws layout (float offsets)
#define WS_V        0        // 1024
#define WS_BIAS     1024     // 4096
#define WS_ATTN     8192     // 2048
#define WS_H0       10240    // 32768
#define WS_H1       43008    // 32768
#define WS_WEIGHTED 75776    // 32768
#define WS_XPROJ    131072   // 4194304

// d_out layout (float offsets): outputs, h, c, attentions
#define OUT_H   1048576
#define OUT_CC  1081344
#define OUT_AT  1114112

__global__ __launch_bounds__(256) void k_prep(const float* __restrict__ W1, const float* __restrict__ W2,
                                              const float* __restrict__ bih, const float* __restrict__ bhh,
                                              float* __restrict__ ws, float* __restrict__ out) {
  int blk = blockIdx.x, tid = threadIdx.x;
  if (blk < 4) {
    // v[c] = sum_a W1_x[a][c] * W2[a]
    int c = blk * 256 + tid;
    float acc = 0.f;
#pragma unroll 8
    for (int a = 0; a < 128; ++a) acc += W1[a * 2048 + 1024 + c] * W2[a];
    ws[WS_V + c] = acc;
  } else if (blk < 20) {
    int j = (blk - 4) * 256 + tid;
    ws[WS_BIAS + j] = bih[j] + bhh[j];
  } else if (blk < 24) {
    // zero c in d_out
    int base = OUT_CC + (blk - 20) * 8192;
    for (int i = 0; i < 32; ++i) out[base + i * 256 + tid] = 0.f;
  } else if (blk < 28) {
    // zero h buffer 0
    int base = WS_H0 + (blk - 24) * 8192;
    for (int i = 0; i < 32; ++i) ws[base + i * 256 + tid] = 0.f;
  }
}

__global__ __launch_bounds__(256) void k_attn(const float* __restrict__ ctx, float* __restrict__ ws) {
  int b = blockIdx.x, tid = threadIdx.x;
  int lane = tid & 63, w = tid >> 6;
  __shared__ float v_s[1024];
  __shared__ float sc_s[64];
  __shared__ float att_s[64];
  for (int i = 0; i < 4; ++i) v_s[tid + i * 256] = ws[WS_V + tid + i * 256];
  __syncthreads();
  // scores[b][s] = dot(xt[b,s,:], v);  xt[b,s,c] = ctx[(s*B+b)*C + c]
  for (int si = 0; si < 16; ++si) {
    int s = w * 16 + si;
    const float* xr = ctx + (s * B_ + b) * C_;
    float acc = 0.f;
#pragma unroll
    for (int i = 0; i < 16; ++i) { int c = lane + i * 64; acc += xr[c] * v_s[c]; }
    for (int off = 32; off; off >>= 1) acc += __shfl_down(acc, off);
    if (lane == 0) sc_s[s] = acc;
  }
  __syncthreads();
  if (tid < 64) {
    float val = sc_s[tid];
    float mx = val;
    for (int off = 32; off; off >>= 1) mx = fmaxf(mx, __shfl_xor(mx, off));
    float e = expf(val - mx);
    float sm = e;
    for (int off = 32; off; off >>= 1) sm += __shfl_xor(sm, off);
    float a = e / sm;
    att_s[tid] = a;
    ws[WS_ATTN + b * 64 + tid] = a;
  }
  __syncthreads();
  // weighted[b][c] = sum_s attn[s] * xt[b,s,c]
  for (int q = 0; q < 4; ++q) {
    int c = tid + q * 256;
    float acc = 0.f;
    for (int s = 0; s < 64; ++s) acc += att_s[s] * ctx[(s * B_ + b) * C_ + c];
    ws[WS_WEIGHTED + b * 1024 + c] = acc;
  }
}

__global__ __launch_bounds__(256) void k_bcast(const float* __restrict__ ws, float* __restrict__ out) {
  int blk = blockIdx.x, tid = threadIdx.x;
  int t = blk >> 5, b = blk & 31;
  const float4* src = reinterpret_cast<const float4*>(ws + WS_WEIGHTED + b * 1024);
  float4* dst = reinterpret_cast<float4*>(out + (t * B_ + b) * C_);
  dst[tid] = src[tid];
  if (tid < 64) out[OUT_AT + (t * B_ + b) * 64 + tid] = ws[WS_ATTN + b * 64 + tid];
}

// x_proj[m][j] = sum_k inputs[m][k]*W_ih[j][k] + bias[j];  m in [0,1024), j in [0,4096)
__global__ __launch_bounds__(256) void k_xproj(const float* __restrict__ inp, const float* __restrict__ Wih,
                                               float* __restrict__ ws) {
  __shared__ float At[32][68];  // [k][m] transposed
  __shared__ float Bt[32][68];  // [k][j] transposed
  int tid = threadIdx.x;
  int m0 = (blockIdx.x >> 6) << 6;
  int j0 = (blockIdx.x & 63) << 6;
  int tx = tid & 15, ty = tid >> 4;
  float acc[4][4] = {};
  for (int k0 = 0; k0 < 1024; k0 += 32) {
    __syncthreads();
#pragma unroll
    for (int i = 0; i < 8; ++i) {
      int e = tid + i * 256;
      int row = e >> 5, col = e & 31;
      At[col][row] = inp[(m0 + row) * 1024 + k0 + col];
      Bt[col][row] = Wih[(j0 + row) * 1024 + k0 + col];
    }
    __syncthreads();
#pragma unroll
    for (int k = 0; k < 32; ++k) {
      float4 a = *reinterpret_cast<const float4*>(&At[k][ty * 4]);
      float4 bb = *reinterpret_cast<const float4*>(&Bt[k][tx * 4]);
      acc[0][0] += a.x * bb.x; acc[0][1] += a.x * bb.y; acc[0][2] += a.x * bb.z; acc[0][3] += a.x * bb.w;
      acc[1][0] += a.y * bb.x; acc[1][1] += a.y * bb.y; acc[1][2] += a.y * bb.z; acc[1][3] += a.y * bb.w;
      acc[2][0] += a.z * bb.x; acc[2][1] += a.z * bb.y; acc[2][2] += a.z * bb.z; acc[2][3] += a.z * bb.w;
      acc[3][0] += a.w * bb.x; acc[3][1] += a.w * bb.y; acc[3][2] += a.w * bb.z; acc[3][3] += a.w * bb.w;
    }
  }
  const float* bias = ws + WS_BIAS;
#pragma unroll
  for (int mi = 0; mi < 4; ++mi) {
    int m = m0 + ty * 4 + mi;
    int j = j0 + tx * 4;
    float4 r;
    r.x = acc[mi][0] + bias[j + 0];
    r.y = acc[mi][1] + bias[j + 1];
    r.z = acc[mi][2] + bias[j + 2];
    r.w = acc[mi][3] + bias[j + 3];
    *reinterpret_cast<float4*>(&ws[WS_XPROJ + m * 4096 + j]) = r;
  }
}

// One LSTM step: gates = x_proj[t] + h @ W_hh^T ; update c,h.
// 256 blocks, block owns h-indices [4*blk, 4*blk+4) and all 4 gates for them.
__global__ __launch_bounds__(256) void k_step(const float* __restrict__ Whh, float* __restrict__ ws,
                                              float* __restrict__ out, int t) {
  __shared__ float h_s[32][132];
  __shared__ float W_s[16][132];
  __shared__ float g_s[16][32];
  int tid = threadIdx.x;
  int hb = blockIdx.x * 4;
  int b = tid & 31, jj = tid >> 5;  // jj in [0,8)
  const float* h_in = ws + ((t & 1) ? WS_H1 : WS_H0);
  float* h_out_buf = ws + ((t & 1) ? WS_H0 : WS_H1);
  int r0 = jj, r1 = jj + 8;
  int j_r0 = (r0 >> 2) * 1024 + hb + (r0 & 3);
  int j_r1 = (r1 >> 2) * 1024 + hb + (r1 & 3);
  float acc0 = 0.f, acc1 = 0.f;
  for (int kc = 0; kc < 1024; kc += 128) {
    __syncthreads();
#pragma unroll
    for (int i = 0; i < 16; ++i) {
      int e = tid + i * 256;
      int bb = e >> 7, k = e & 127;
      h_s[bb][k] = h_in[bb * 1024 + kc + k];
    }
#pragma unroll
    for (int i = 0; i < 8; ++i) {
      int e = tid + i * 256;
      int r = e >> 7, k = e & 127;
      int j = (r >> 2) * 1024 + hb + (r & 3);
      W_s[r][k] = Whh[j * 1024 + kc + k];
    }
    __syncthreads();
#pragma unroll
    for (int k4 = 0; k4 < 128; k4 += 4) {
      float4 hv = *reinterpret_cast<const float4*>(&h_s[b][k4]);
      float4 w0 = *reinterpret_cast<const float4*>(&W_s[r0][k4]);
      float4 w1 = *reinterpret_cast<const float4*>(&W_s[r1][k4]);
      acc0 += hv.x * w0.x + hv.y * w0.y + hv.z * w0.z + hv.w * w0.w;
      acc1 += hv.x * w1.x + hv.y * w1.y + hv.z * w1.z + hv.w * w1.w;
    }
  }
  const float* xp = ws + WS_XPROJ + (size_t)(t * 32) * 4096;
  g_s[r0][b] = acc0 + xp[b * 4096 + j_r0];
  g_s[r1][b] = acc1 + xp[b * 4096 + j_r1];
  __syncthreads();
  if (tid < 128) {
    int bb = tid & 31, hi = tid >> 5;
    float ig = g_s[0 + hi][bb];
    float fg = g_s[4 + hi][bb];
    float gg = g_s[8 + hi][bb];
    float og = g_s[12 + hi][bb];
    int hidx = hb + hi;
    float c_old = out[OUT_CC + bb * 1024 + hidx];
    float si = 1.f / (1.f + expf(-ig));
    float sf = 1.f / (1.f + expf(-fg));
    float so = 1.f / (1.f + expf(-og));
    float c_new = sf * c_old + si * tanhf(gg);
    float h_new = so * tanhf(c_new);
    out[OUT_CC + bb * 1024 + hidx] = c_new;
    h_out_buf[bb * 1024 + hidx] = h_new;
    if (t == 31) out[OUT_H + bb * 1024 + hidx] = h_new;
  }
}

extern "C" void kernel_launch(void* const* d_in, const int* in_sizes, int n_in,
                              void* d_out, int out_size, void* d_ws, size_t ws_size,
                              hipStream_t stream) {
  const float* inp = (const float*)d_in[0];
  const float* ctx = (const float*)d_in[1];
  const float* Wih = (const float*)d_in[2];
  const float* Whh = (const float*)d_in[3];
  const float* bih = (const float*)d_in[4];
  const float* bhh = (const float*)d_in[5];
  const float* W1  = (const float*)d_in[6];
  const float* W2  = (const float*)d_in[8];
  float* out = (float*)d_out;
  float* ws = (float*)d_ws;

  hipLaunchKernelGGL(k_prep, dim3(32), dim3(256), 0, stream, W1, W2, bih, bhh, ws, out);
  hipLaunchKernelGGL(k_attn, dim3(32), dim3(256), 0, stream, ctx, ws);
  hipLaunchKernelGGL(k_bcast, dim3(1024), dim3(256), 0, stream, ws, out);
  hipLaunchKernelGGL(k_xproj, dim3(1024), dim3(256), 0, stream, inp, Wih, ws);
  for (int t = 0; t < T_; ++t)
    hipLaunchKernelGGL(k_step, dim3(256), dim3(256), 0, stream, Whh, ws, out, t);
}

// Round 3
// 536.877 us; speedup vs baseline: 3.4563x; 3.4563x over previous
//
#include <hip/hip_runtime.h>

#define T_ 32
#define B_ 32
#define S_ 64
#define C_ 1024
#define H_ 1024

typedef __attribute__((ext_vector_type(8))) short bf16x8;
typedef __attribute__((ext_vector_type(4))) float f32x4;

// d_out layout (float offsets): outputs[32*32*1024], h[32*1024], c[32*1024], attn[32*32*64]
#define OUT_H   1048576
#define OUT_CC  1081344
#define OUT_AT  1114112

__device__ __forceinline__ ushort f2b(float f) {
  unsigned u = __float_as_uint(f);
  unsigned r = (u + 0x7FFFu + ((u >> 16) & 1u)) >> 16;
  return (ushort)r;
}
__device__ __forceinline__ float b2f(ushort h) {
  return __uint_as_float(((unsigned)h) << 16);
}

// ---------------- convert f32 -> bf16 (8 elems/thread) ----------------
__global__ __launch_bounds__(256) void k_cvt(const float* __restrict__ src, ushort* __restrict__ dst) {
  size_t i = ((size_t)blockIdx.x * 256 + threadIdx.x) * 8;
  float4 v0 = *reinterpret_cast<const float4*>(src + i);
  float4 v1 = *reinterpret_cast<const float4*>(src + i + 4);
  uint4 o;
  o.x = (unsigned)f2b(v0.x) | ((unsigned)f2b(v0.y) << 16);
  o.y = (unsigned)f2b(v0.z) | ((unsigned)f2b(v0.w) << 16);
  o.z = (unsigned)f2b(v1.x) | ((unsigned)f2b(v1.y) << 16);
  o.w = (unsigned)f2b(v1.z) | ((unsigned)f2b(v1.w) << 16);
  *reinterpret_cast<uint4*>(dst + i) = o;
}

// ---------------- prep: v = W2@W1_x, bias, zero c & h0 ----------------
__global__ __launch_bounds__(256) void k_prep(const float* __restrict__ W1, const float* __restrict__ W2,
                                              const float* __restrict__ bih, const float* __restrict__ bhh,
                                              float* __restrict__ v, float* __restrict__ bias,
                                              ushort* __restrict__ h0, float* __restrict__ out) {
  int blk = blockIdx.x, tid = threadIdx.x;
  if (blk < 4) {
    int c = blk * 256 + tid;
    float acc = 0.f;
#pragma unroll 8
    for (int a = 0; a < 128; ++a) acc += W1[a * 2048 + 1024 + c] * W2[a];
    v[c] = acc;
  } else if (blk < 20) {
    int j = (blk - 4) * 256 + tid;
    bias[j] = bih[j] + bhh[j];
  } else if (blk < 24) {
    int base = OUT_CC + (blk - 20) * 8192;
    for (int i = 0; i < 32; ++i) out[base + i * 256 + tid] = 0.f;
  } else if (blk < 28) {
    unsigned* hz = reinterpret_cast<unsigned*>(h0);
    int base = (blk - 24) * 4096;
    for (int i = 0; i < 16; ++i) hz[base + i * 256 + tid] = 0u;
  }
}

// ---------------- attention (time-invariant) ----------------
__global__ __launch_bounds__(256) void k_attn(const float* __restrict__ ctx, const float* __restrict__ v,
                                              float* __restrict__ attn, float* __restrict__ wgt) {
  int b = blockIdx.x, tid = threadIdx.x;
  int lane = tid & 63, w = tid >> 6;
  __shared__ float v_s[1024];
  __shared__ float sc_s[64];
  __shared__ float att_s[64];
  for (int i = 0; i < 4; ++i) v_s[tid + i * 256] = v[tid + i * 256];
  __syncthreads();
  for (int si = 0; si < 16; ++si) {
    int s = w * 16 + si;
    const float* xr = ctx + (size_t)(s * B_ + b) * C_;
    float acc = 0.f;
#pragma unroll
    for (int i = 0; i < 16; ++i) { int c = lane + i * 64; acc += xr[c] * v_s[c]; }
    for (int off = 32; off; off >>= 1) acc += __shfl_down(acc, off);
    if (lane == 0) sc_s[s] = acc;
  }
  __syncthreads();
  if (tid < 64) {
    float val = sc_s[tid];
    float mx = val;
    for (int off = 32; off; off >>= 1) mx = fmaxf(mx, __shfl_xor(mx, off));
    float e = expf(val - mx);
    float sm = e;
    for (int off = 32; off; off >>= 1) sm += __shfl_xor(sm, off);
    float a = e / sm;
    att_s[tid] = a;
    attn[b * 64 + tid] = a;
  }
  __syncthreads();
  const float4* ctx4 = reinterpret_cast<const float4*>(ctx);
  float4 a4 = {0.f, 0.f, 0.f, 0.f};
  for (int s = 0; s < 64; ++s) {
    float a = att_s[s];
    float4 x = ctx4[(size_t)(s * B_ + b) * 256 + tid];
    a4.x += a * x.x; a4.y += a * x.y; a4.z += a * x.z; a4.w += a * x.w;
  }
  reinterpret_cast<float4*>(wgt + b * 1024)[tid] = a4;
}

__global__ __launch_bounds__(256) void k_bcast(const float* __restrict__ wgt, const float* __restrict__ attn,
                                               float* __restrict__ out) {
  int blk = blockIdx.x, tid = threadIdx.x;
  int t = blk >> 5, b = blk & 31;
  const float4* src = reinterpret_cast<const float4*>(wgt + b * 1024);
  float4* dst = reinterpret_cast<float4*>(out + (size_t)(t * B_ + b) * C_);
  dst[tid] = src[tid];
  if (tid < 64) out[OUT_AT + (t * B_ + b) * 64 + tid] = attn[b * 64 + tid];
}

// ---------------- x_proj MFMA: [1024 x 4096] = inp[1024x1024] @ Wih^T + bias ----------------
__global__ __launch_bounds__(256) void k_xproj(const ushort* __restrict__ inpb, const ushort* __restrict__ Wihb,
                                               const float* __restrict__ bias, ushort* __restrict__ xpb) {
  __shared__ int4 A_s[512];  // fragment-contiguous: [kgrp(4)][row(128)] x 16B
  __shared__ int4 B_s[512];
  int tid = threadIdx.x;
  int m0 = (blockIdx.x >> 5) << 7;
  int j0 = (blockIdx.x & 31) << 7;
  int lane = tid & 63, w = tid >> 6;
  int wm = (w >> 1) * 64, wn = (w & 1) * 64;
  int g = lane >> 4, r = lane & 15;
  f32x4 acc[4][4];
#pragma unroll
  for (int mi = 0; mi < 4; ++mi)
#pragma unroll
    for (int ni = 0; ni < 4; ++ni) acc[mi][ni] = (f32x4)(0.f);

  int f0 = tid, r0s = f0 >> 2, g0s = f0 & 3;
  int f1 = tid + 256, r1s = f1 >> 2, g1s = f1 & 3;
  for (int k0 = 0; k0 < 1024; k0 += 32) {
    __syncthreads();
    A_s[g0s * 128 + r0s] = *reinterpret_cast<const int4*>(inpb + (size_t)(m0 + r0s) * 1024 + k0 + g0s * 8);
    B_s[g0s * 128 + r0s] = *reinterpret_cast<const int4*>(Wihb + (size_t)(j0 + r0s) * 1024 + k0 + g0s * 8);
    A_s[g1s * 128 + r1s] = *reinterpret_cast<const int4*>(inpb + (size_t)(m0 + r1s) * 1024 + k0 + g1s * 8);
    B_s[g1s * 128 + r1s] = *reinterpret_cast<const int4*>(Wihb + (size_t)(j0 + r1s) * 1024 + k0 + g1s * 8);
    __syncthreads();
    bf16x8 af[4], bf_[4];
#pragma unroll
    for (int mi = 0; mi < 4; ++mi) af[mi] = *reinterpret_cast<const bf16x8*>(&A_s[g * 128 + wm + mi * 16 + r]);
#pragma unroll
    for (int ni = 0; ni < 4; ++ni) bf_[ni] = *reinterpret_cast<const bf16x8*>(&B_s[g * 128 + wn + ni * 16 + r]);
#pragma unroll
    for (int mi = 0; mi < 4; ++mi)
#pragma unroll
      for (int ni = 0; ni < 4; ++ni)
        acc[mi][ni] = __builtin_amdgcn_mfma_f32_16x16x32_bf16(af[mi], bf_[ni], acc[mi][ni], 0, 0, 0);
  }
  int q = lane >> 4;
#pragma unroll
  for (int ni = 0; ni < 4; ++ni) {
    int j = j0 + wn + ni * 16 + r;
    float bj = bias[j];
#pragma unroll
    for (int mi = 0; mi < 4; ++mi) {
#pragma unroll
      for (int e = 0; e < 4; ++e) {
        int m = m0 + wm + mi * 16 + q * 4 + e;
        xpb[(size_t)m * 4096 + j] = f2b(acc[mi][ni][e] + bj);
      }
    }
  }
}

// ---------------- one LSTM step via MFMA ----------------
// 64 WGs; WG owns hidx [16*blk, 16*blk+16); wave w computes gate w (16 rows x 32 b, K=1024).
__global__ __launch_bounds__(256) void k_step(const ushort* __restrict__ Whhb, const ushort* __restrict__ xpb,
                                              const ushort* __restrict__ hin, ushort* __restrict__ hout,
                                              float* __restrict__ out, int t) {
  int tid = threadIdx.x, lane = tid & 63, w = tid >> 6;
  int hidx0 = blockIdx.x * 16;
  int g = lane >> 4, r = lane & 15;
  int J0 = w * 1024 + hidx0;
  const ushort* Arow = Whhb + (size_t)(J0 + r) * 1024 + g * 8;
  const ushort* Bp0 = hin + (size_t)r * 1024 + g * 8;
  const ushort* Bp1 = hin + (size_t)(r + 16) * 1024 + g * 8;
  f32x4 acc0 = (f32x4)(0.f), acc1 = (f32x4)(0.f);
#pragma unroll 8
  for (int kk = 0; kk < 32; ++kk) {
    bf16x8 a = *reinterpret_cast<const bf16x8*>(Arow + kk * 32);
    bf16x8 b0 = *reinterpret_cast<const bf16x8*>(Bp0 + kk * 32);
    bf16x8 b1 = *reinterpret_cast<const bf16x8*>(Bp1 + kk * 32);
    acc0 = __builtin_amdgcn_mfma_f32_16x16x32_bf16(a, b0, acc0, 0, 0, 0);
    acc1 = __builtin_amdgcn_mfma_f32_16x16x32_bf16(a, b1, acc1, 0, 0, 0);
  }
  __shared__ float g_s[4][16][33];
#pragma unroll
  for (int e = 0; e < 4; ++e) {
    g_s[w][g * 4 + e][r] = acc0[e];
    g_s[w][g * 4 + e][r + 16] = acc1[e];
  }
  __syncthreads();
#pragma unroll
  for (int i = 0; i < 2; ++i) {
    int cell = tid + i * 256;
    int b = cell & 31, jr = cell >> 5;
    int hidx = hidx0 + jr;
    const ushort* xr = xpb + (size_t)(t * 32 + b) * 4096;
    float ig = g_s[0][jr][b] + b2f(xr[hidx]);
    float fg = g_s[1][jr][b] + b2f(xr[1024 + hidx]);
    float gg = g_s[2][jr][b] + b2f(xr[2048 + hidx]);
    float og = g_s[3][jr][b] + b2f(xr[3072 + hidx]);
    float si = 1.f / (1.f + __expf(-ig));
    float sf = 1.f / (1.f + __expf(-fg));
    float so = 1.f / (1.f + __expf(-og));
    float c_old = out[OUT_CC + b * 1024 + hidx];
    float c_new = sf * c_old + si * tanhf(gg);
    float h_new = so * tanhf(c_new);
    out[OUT_CC + b * 1024 + hidx] = c_new;
    hout[b * 1024 + hidx] = f2b(h_new);
    if (t == 31) out[OUT_H + b * 1024 + hidx] = h_new;
  }
}

extern "C" void kernel_launch(void* const* d_in, const int* in_sizes, int n_in,
                              void* d_out, int out_size, void* d_ws, size_t ws_size,
                              hipStream_t stream) {
  const float* inp = (const float*)d_in[0];
  const float* ctx = (const float*)d_in[1];
  const float* Wih = (const float*)d_in[2];
  const float* Whh = (const float*)d_in[3];
  const float* bih = (const float*)d_in[4];
  const float* bhh = (const float*)d_in[5];
  const float* W1  = (const float*)d_in[6];
  const float* W2  = (const float*)d_in[8];
  float* out = (float*)d_out;
  char* wsb = (char*)d_ws;

  float* v    = (float*)(wsb + 0);        // 4 KB
  float* bias = (float*)(wsb + 4096);     // 16 KB
  float* attn = (float*)(wsb + 20480);    // 8 KB
  float* wgt  = (float*)(wsb + 28672);    // 128 KB
  ushort* h0   = (ushort*)(wsb + 163840);   // 64 KB
  ushort* h1   = (ushort*)(wsb + 229376);   // 64 KB
  ushort* inpb = (ushort*)(wsb + 294912);   // 2 MB
  ushort* Wihb = (ushort*)(wsb + 2392064);  // 8 MB
  ushort* Whhb = (ushort*)(wsb + 10780672); // 8 MB
  ushort* xpb  = (ushort*)(wsb + 19169280); // 8 MB

  hipLaunchKernelGGL(k_prep, dim3(28), dim3(256), 0, stream, W1, W2, bih, bhh, v, bias, h0, out);
  hipLaunchKernelGGL(k_cvt, dim3(512), dim3(256), 0, stream, inp, inpb);
  hipLaunchKernelGGL(k_cvt, dim3(2048), dim3(256), 0, stream, Wih, Wihb);
  hipLaunchKernelGGL(k_cvt, dim3(2048), dim3(256), 0, stream, Whh, Whhb);
  hipLaunchKernelGGL(k_attn, dim3(32), dim3(256), 0, stream, ctx, v, attn, wgt);
  hipLaunchKernelGGL(k_bcast, dim3(1024), dim3(256), 0, stream, wgt, attn, out);
  hipLaunchKernelGGL(k_xproj, dim3(256), dim3(256), 0, stream, inpb, Wihb, bias, xpb);
  for (int t = 0; t < T_; ++t) {
    const ushort* hin = (t & 1) ? h1 : h0;
    ushort* hout = (t & 1) ? h0 : h1;
    hipLaunchKernelGGL(k_step, dim3(64), dim3(256), 0, stream, Whhb, xpb, hin, hout, out, t);
  }
}